// Round 1
// baseline (177.372 us; speedup 1.0000x reference)
//
#include <hip/hip_runtime.h>

// GraphNorm: per-graph (segmented) normalization over sorted batch ids.
// N=500000 rows, C=128 channels, B=512 graphs (reference constants).
//
// Pass 0: starts[b] = lower_bound(batch, b)  (b in [0, B]) -> segment bounds
// Pass 1: per graph b: sum[c], sumsq[c] over its rows (single read of x);
//         fold into affine coeffs a[b][c], d[b][c]:
//           mean = sum/cnt; ex2 = sumsq/cnt
//           var  = ex2 - mean^2 * ms * (2 - ms)     // == E[(x-mean*ms)^2]
//           rstd = rsqrt(var + 1e-5)
//           a = w * rstd;  d = bias - a * mean * ms
// Pass 2: out[n][c] = fma(a[batch[n]][c], x[n][c], d[batch[n]][c])

#define C_CH 128
#define EPSV 1e-5f

__global__ void gn_bounds(const int* __restrict__ batch, int N, int B,
                          int* __restrict__ starts) {
    int b = blockIdx.x * blockDim.x + threadIdx.x;
    if (b > B) return;
    int lo = 0, hi = N;
    while (lo < hi) {
        int mid = (lo + hi) >> 1;
        if (batch[mid] < b) lo = mid + 1; else hi = mid;
    }
    starts[b] = lo;  // for b==B all values < B, so starts[B]==N
}

// One block (256 threads) per graph. Thread t owns float4-column (t&31),
// row-group (t>>5) striding by 8 rows.
__global__ __launch_bounds__(256) void gn_stats(
    const float* __restrict__ x, const int* __restrict__ starts,
    const float* __restrict__ w, const float* __restrict__ bias,
    const float* __restrict__ ms, float* __restrict__ A, float* __restrict__ D) {
    const int b   = blockIdx.x;
    const int tid = threadIdx.x;
    const int col = tid & 31;   // float4 column: channels 4*col .. 4*col+3
    const int rg  = tid >> 5;   // row group 0..7

    const int s = starts[b];
    const int e = starts[b + 1];

    const float4* __restrict__ x4 = (const float4*)x;

    float4 sum = make_float4(0.f, 0.f, 0.f, 0.f);
    float4 sq  = make_float4(0.f, 0.f, 0.f, 0.f);
    for (int r = s + rg; r < e; r += 8) {
        float4 v = x4[(size_t)r * (C_CH / 4) + col];
        sum.x += v.x; sum.y += v.y; sum.z += v.z; sum.w += v.w;
        sq.x += v.x * v.x; sq.y += v.y * v.y;
        sq.z += v.z * v.z; sq.w += v.w * v.w;
    }

    __shared__ float4 s_sum[8][32];
    __shared__ float4 s_sq[8][32];
    s_sum[rg][col] = sum;
    s_sq[rg][col]  = sq;
    __syncthreads();

    if (tid < 32) {
        float4 ts = s_sum[0][col];
        float4 tq = s_sq[0][col];
        #pragma unroll
        for (int g = 1; g < 8; ++g) {
            float4 a = s_sum[g][col];
            float4 q = s_sq[g][col];
            ts.x += a.x; ts.y += a.y; ts.z += a.z; ts.w += a.w;
            tq.x += q.x; tq.y += q.y; tq.z += q.z; tq.w += q.w;
        }
        const int cnt = e - s;
        const float inv = 1.0f / (float)max(cnt, 1);
        float sums[4] = {ts.x, ts.y, ts.z, ts.w};
        float sqs[4]  = {tq.x, tq.y, tq.z, tq.w};
        #pragma unroll
        for (int j = 0; j < 4; ++j) {
            const int c   = col * 4 + j;
            const float m   = sums[j] * inv;
            const float ex2 = sqs[j] * inv;
            const float msc = ms[c];
            const float var = ex2 - m * m * msc * (2.0f - msc);
            const float rstd = rsqrtf(var + EPSV);
            const float a = w[c] * rstd;
            const float d = bias[c] - a * m * msc;
            A[b * C_CH + c] = a;
            D[b * C_CH + c] = d;
        }
    }
}

__global__ __launch_bounds__(256) void gn_apply(
    const float* __restrict__ x, const int* __restrict__ batch,
    const float* __restrict__ A, const float* __restrict__ D,
    float* __restrict__ out, int n4) {
    int g = blockIdx.x * blockDim.x + threadIdx.x;
    if (g >= n4) return;
    const int row = g >> 5;   // C/4 = 32 float4 per row
    const int c4  = g & 31;
    const int b   = batch[row];

    const float4* __restrict__ x4 = (const float4*)x;
    const float4* __restrict__ A4 = (const float4*)A;
    const float4* __restrict__ D4 = (const float4*)D;
    float4* __restrict__ o4 = (float4*)out;

    float4 v = x4[g];
    float4 a = A4[b * (C_CH / 4) + c4];
    float4 d = D4[b * (C_CH / 4) + c4];
    float4 r;
    r.x = fmaf(a.x, v.x, d.x);
    r.y = fmaf(a.y, v.y, d.y);
    r.z = fmaf(a.z, v.z, d.z);
    r.w = fmaf(a.w, v.w, d.w);
    o4[g] = r;
}

extern "C" void kernel_launch(void* const* d_in, const int* in_sizes, int n_in,
                              void* d_out, int out_size, void* d_ws, size_t ws_size,
                              hipStream_t stream) {
    const float* x     = (const float*)d_in[0];
    const int*   batch = (const int*)d_in[1];
    const float* w     = (const float*)d_in[2];
    const float* bias  = (const float*)d_in[3];
    const float* ms    = (const float*)d_in[4];
    // d_in[5] = batch_size (device scalar); grid size needs it host-side ->
    // use the reference constant B=512.
    const int B = 512;
    const int N = in_sizes[1];          // rows
    // workspace layout: starts[B+1] @ 0 (4KB pad), A[B*C] @ 4096, D[B*C] next
    int*   starts = (int*)d_ws;
    float* A = (float*)((char*)d_ws + 4096);
    float* D = (float*)((char*)d_ws + 4096 + (size_t)B * C_CH * sizeof(float));
    float* out = (float*)d_out;

    gn_bounds<<<(B + 1 + 255) / 256, 256, 0, stream>>>(batch, N, B, starts);
    gn_stats<<<B, 256, 0, stream>>>(x, starts, w, bias, ms, A, D);
    const int n4 = N * (C_CH / 4);
    gn_apply<<<(n4 + 255) / 256, 256, 0, stream>>>(x, batch, A, D, out, n4);
}

// Round 2
// 155.280 us; speedup vs baseline: 1.1423x; 1.1423x over previous
//
#include <hip/hip_runtime.h>

// GraphNorm: per-graph (segmented) normalization over sorted batch ids.
// N=500000 rows, C=128 channels, B=512 graphs (reference constants).
//
// Pass 0: starts[b] = lower_bound(batch, b)  (b in [0, B]) -> segment bounds
// Pass 1: 4 blocks per graph compute deterministic partial sum/sumsq per
//         channel, written to private (q,b,c) slots (no atomics).
// Pass 2: coeff kernel folds 4 partials -> affine coeffs a[b][c], d[b][c]:
//           mean = sum/cnt; ex2 = sumsq/cnt
//           var  = ex2 - mean^2 * ms * (2 - ms)     // == E[(x-mean*ms)^2]
//           rstd = rsqrt(var + 1e-5)
//           a = w * rstd;  d = bias - a * mean * ms
// Pass 3: out[n][c] = fma(a[batch[n]][c], x[n][c], d[batch[n]][c])

#define C_CH 128
#define B_GR 512
#define QSPLIT 4
#define EPSV 1e-5f

__global__ void gn_bounds(const int* __restrict__ batch, int N, int B,
                          int* __restrict__ starts) {
    int b = blockIdx.x * blockDim.x + threadIdx.x;
    if (b > B) return;
    int lo = 0, hi = N;
    while (lo < hi) {
        int mid = (lo + hi) >> 1;
        if (batch[mid] < b) lo = mid + 1; else hi = mid;
    }
    starts[b] = lo;  // for b==B all values < B, so starts[B]==N
}

// Grid = B*QSPLIT blocks, 256 threads. Block (b,q): thread t owns float4-col
// (t&31), row-group (t>>5); rows s + q*8 + rg, striding 32.
__global__ __launch_bounds__(256) void gn_stats(
    const float* __restrict__ x, const int* __restrict__ starts,
    float4* __restrict__ S, float4* __restrict__ Q) {
    const int g   = blockIdx.x;
    const int b   = g >> 2;
    const int q   = g & 3;
    const int tid = threadIdx.x;
    const int col = tid & 31;   // float4 column: channels 4*col .. 4*col+3
    const int rg  = tid >> 5;   // row group 0..7

    const int s = starts[b];
    const int e = starts[b + 1];

    const float4* __restrict__ x4 = (const float4*)x;

    float4 sum = make_float4(0.f, 0.f, 0.f, 0.f);
    float4 sq  = make_float4(0.f, 0.f, 0.f, 0.f);
    for (int r = s + q * 8 + rg; r < e; r += 32) {
        float4 v = x4[(size_t)r * (C_CH / 4) + col];
        sum.x += v.x; sum.y += v.y; sum.z += v.z; sum.w += v.w;
        sq.x += v.x * v.x; sq.y += v.y * v.y;
        sq.z += v.z * v.z; sq.w += v.w * v.w;
    }

    __shared__ float4 s_sum[8][32];
    __shared__ float4 s_sq[8][32];
    s_sum[rg][col] = sum;
    s_sq[rg][col]  = sq;
    __syncthreads();

    if (tid < 32) {
        float4 ts = s_sum[0][col];
        float4 tq = s_sq[0][col];
        #pragma unroll
        for (int gg = 1; gg < 8; ++gg) {
            float4 a = s_sum[gg][col];
            float4 p = s_sq[gg][col];
            ts.x += a.x; ts.y += a.y; ts.z += a.z; ts.w += a.w;
            tq.x += p.x; tq.y += p.y; tq.z += p.z; tq.w += p.w;
        }
        // partial slot (q, b, col)
        const size_t slot = ((size_t)q * B_GR + b) * (C_CH / 4) + col;
        S[slot] = ts;
        Q[slot] = tq;
    }
}

// B*C threads: fold QSPLIT partials -> A, D
__global__ __launch_bounds__(256) void gn_coeff(
    const float* __restrict__ S, const float* __restrict__ Q,
    const int* __restrict__ starts,
    const float* __restrict__ w, const float* __restrict__ bias,
    const float* __restrict__ ms,
    float* __restrict__ A, float* __restrict__ D) {
    const int idx = blockIdx.x * blockDim.x + threadIdx.x;
    if (idx >= B_GR * C_CH) return;
    const int b = idx >> 7;        // / C_CH
    const int c = idx & (C_CH - 1);

    float sum = 0.f, sq = 0.f;
    #pragma unroll
    for (int q = 0; q < QSPLIT; ++q) {
        const size_t slot = ((size_t)q * B_GR + b) * C_CH + c;
        sum += S[slot];
        sq  += Q[slot];
    }
    const int cnt = starts[b + 1] - starts[b];
    const float inv = 1.0f / (float)max(cnt, 1);
    const float m   = sum * inv;
    const float ex2 = sq * inv;
    const float msc = ms[c];
    const float var = ex2 - m * m * msc * (2.0f - msc);
    const float rstd = rsqrtf(var + EPSV);
    const float a = w[c] * rstd;
    A[idx] = a;
    D[idx] = bias[c] - a * m * msc;
}

__global__ __launch_bounds__(256) void gn_apply(
    const float* __restrict__ x, const int* __restrict__ batch,
    const float* __restrict__ A, const float* __restrict__ D,
    float* __restrict__ out, int n4) {
    int g = blockIdx.x * blockDim.x + threadIdx.x;
    if (g >= n4) return;
    const int row = g >> 5;   // C/4 = 32 float4 per row
    const int c4  = g & 31;
    const int b   = batch[row];

    const float4* __restrict__ x4 = (const float4*)x;
    const float4* __restrict__ A4 = (const float4*)A;
    const float4* __restrict__ D4 = (const float4*)D;
    float4* __restrict__ o4 = (float4*)out;

    float4 v = x4[g];
    float4 a = A4[b * (C_CH / 4) + c4];
    float4 d = D4[b * (C_CH / 4) + c4];
    float4 r;
    r.x = fmaf(a.x, v.x, d.x);
    r.y = fmaf(a.y, v.y, d.y);
    r.z = fmaf(a.z, v.z, d.z);
    r.w = fmaf(a.w, v.w, d.w);
    o4[g] = r;
}

extern "C" void kernel_launch(void* const* d_in, const int* in_sizes, int n_in,
                              void* d_out, int out_size, void* d_ws, size_t ws_size,
                              hipStream_t stream) {
    const float* x     = (const float*)d_in[0];
    const int*   batch = (const int*)d_in[1];
    const float* w     = (const float*)d_in[2];
    const float* bias  = (const float*)d_in[3];
    const float* ms    = (const float*)d_in[4];
    const int B = B_GR;                 // reference constant (device scalar d_in[5])
    const int N = in_sizes[1];          // rows

    // workspace layout (bytes):
    //   starts: [B+1] int        @ 0        (pad to 4096)
    //   S:      [Q*B*C] float    @ 4096               (1 MB)
    //   Q:      [Q*B*C] float    @ 4096 + 1 MB        (1 MB)
    //   A:      [B*C] float      @ 4096 + 2 MB        (256 KB)
    //   D:      [B*C] float      @ 4096 + 2.25 MB     (256 KB)
    char* ws = (char*)d_ws;
    int*   starts = (int*)ws;
    float* S = (float*)(ws + 4096);
    float* Qb = S + (size_t)QSPLIT * B * C_CH;
    float* A  = Qb + (size_t)QSPLIT * B * C_CH;
    float* D  = A + (size_t)B * C_CH;
    float* out = (float*)d_out;

    gn_bounds<<<(B + 1 + 255) / 256, 256, 0, stream>>>(batch, N, B, starts);
    gn_stats<<<B * QSPLIT, 256, 0, stream>>>(x, starts, (float4*)S, (float4*)Qb);
    gn_coeff<<<(B * C_CH + 255) / 256, 256, 0, stream>>>(S, Qb, starts, w, bias, ms, A, D);
    const int n4 = N * (C_CH / 4);
    gn_apply<<<(n4 + 255) / 256, 256, 0, stream>>>(x, batch, A, D, out, n4);
}

// Round 5
// 123.834 us; speedup vs baseline: 1.4323x; 1.2539x over previous
//
#include <hip/hip_runtime.h>

// GraphNorm: per-graph (segmented) normalization over sorted batch ids.
// N=500000 rows, C=128 channels, B=512 graphs (reference constants).
//
// Pass 0 (gn_bounds): starts[b] = lower_bound(batch, b).
// Pass 1 (gn_fused):  ONE block per graph, 1024 threads, two passes:
//   (a) sum/sumsq over the segment's rows -> LDS tree-reduce -> per-channel
//       affine coeffs in LDS:
//         mean = sum/cnt; ex2 = sumsq/cnt
//         var  = ex2 - mean^2 * ms * (2 - ms)   // == E[(x-mean*ms)^2]
//         a = w * rsqrt(var+eps); d = bias - a * mean * ms
//   (b) re-read the segment (L2/L3-resident: aggregate working set == x ==
//       256MB == L3) and store out = fma(a, x, d) with nt stores so the
//       output stream does not evict x from cache.
// No cross-block communication (R3 failed on XCD L2 non-coherence).

#define C_CH 128
#define B_GR 512
#define EPSV 1e-5f

typedef float f32x4 __attribute__((ext_vector_type(4)));

__global__ void gn_bounds(const int* __restrict__ batch, int N, int B,
                          int* __restrict__ starts) {
    int b = blockIdx.x * blockDim.x + threadIdx.x;
    if (b > B) return;
    int lo = 0, hi = N;
    while (lo < hi) {
        int mid = (lo + hi) >> 1;
        if (batch[mid] < b) lo = mid + 1; else hi = mid;
    }
    starts[b] = lo;  // for b==B all values < B, so starts[B]==N
}

// Grid = B blocks x 1024 threads. Thread t: float4-col (t&31), row-group
// (t>>5) in [0,32); rows s+rg, stride 32.
__global__ __launch_bounds__(1024) void gn_fused(
    const float* __restrict__ x, const int* __restrict__ starts,
    const float* __restrict__ w, const float* __restrict__ bias,
    const float* __restrict__ ms, float* __restrict__ out) {
    const int b   = blockIdx.x;
    const int tid = threadIdx.x;
    const int col = tid & 31;   // float4 column: channels 4*col .. 4*col+3
    const int rg  = tid >> 5;   // row group 0..31

    const int s = starts[b];
    const int e = starts[b + 1];

    const f32x4* __restrict__ x4 = (const f32x4*)x;
    f32x4* __restrict__ o4 = (f32x4*)out;

    // ---- pass 1: per-thread partial sums ----
    f32x4 sum = {0.f, 0.f, 0.f, 0.f};
    f32x4 sq  = {0.f, 0.f, 0.f, 0.f};
    for (int r = s + rg; r < e; r += 32) {
        f32x4 v = x4[(size_t)r * (C_CH / 4) + col];
        sum += v;
        sq  += v * v;
    }

    __shared__ f32x4 s_sum[32][32];   // [rg][col] 16KB
    __shared__ f32x4 s_sq[32][32];    // 16KB
    __shared__ float s_a[C_CH];
    __shared__ float s_d[C_CH];

    s_sum[rg][col] = sum;
    s_sq[rg][col]  = sq;

    // tree-reduce over rg (fixed order -> deterministic)
    #pragma unroll
    for (int st = 16; st >= 1; st >>= 1) {
        __syncthreads();
        if (rg < st) {
            s_sum[rg][col] += s_sum[rg + st][col];
            s_sq[rg][col]  += s_sq[rg + st][col];
        }
    }
    __syncthreads();

    // coeffs: one thread per channel
    if (tid < C_CH) {
        const int c  = tid;
        const int cc = c >> 2;
        const int j  = c & 3;
        const float fsum = s_sum[0][cc][j];
        const float fsq  = s_sq[0][cc][j];
        const int   cnt  = e - s;
        const float inv  = 1.0f / (float)max(cnt, 1);
        const float m    = fsum * inv;
        const float ex2  = fsq * inv;
        const float msc  = ms[c];
        const float var  = ex2 - m * m * msc * (2.0f - msc);
        const float rstd = rsqrtf(var + EPSV);
        const float a    = w[c] * rstd;
        s_a[c] = a;
        s_d[c] = bias[c] - a * m * msc;
    }
    __syncthreads();

    // ---- pass 2: apply (reads hit L2/L3; nt stores for out) ----
    const f32x4 a = ((const f32x4*)s_a)[col];
    const f32x4 d = ((const f32x4*)s_d)[col];
    for (int r = s + rg; r < e; r += 32) {
        const size_t g = (size_t)r * (C_CH / 4) + col;
        f32x4 v = x4[g];
        f32x4 o;
        o.x = fmaf(a.x, v.x, d.x);
        o.y = fmaf(a.y, v.y, d.y);
        o.z = fmaf(a.z, v.z, d.z);
        o.w = fmaf(a.w, v.w, d.w);
        __builtin_nontemporal_store(o, &o4[g]);
    }
}

extern "C" void kernel_launch(void* const* d_in, const int* in_sizes, int n_in,
                              void* d_out, int out_size, void* d_ws, size_t ws_size,
                              hipStream_t stream) {
    const float* x     = (const float*)d_in[0];
    const int*   batch = (const int*)d_in[1];
    const float* w     = (const float*)d_in[2];
    const float* bias  = (const float*)d_in[3];
    const float* ms    = (const float*)d_in[4];
    const int B = B_GR;                 // reference constant (device scalar d_in[5])
    const int N = in_sizes[1];          // rows

    int* starts = (int*)d_ws;           // [B+1] ints
    float* out = (float*)d_out;

    gn_bounds<<<(B + 1 + 255) / 256, 256, 0, stream>>>(batch, N, B, starts);
    gn_fused<<<B, 1024, 0, stream>>>(x, starts, w, bias, ms, out);
}